// Round 1
// baseline (7593.378 us; speedup 1.0000x reference)
//
#include <hip/hip_runtime.h>

#define NBATCH 8
#define NNODE 256
#define NL 32
#define NK 3
#define NH 64
#define NQ (NNODE * NL)   // 8192 = flattened (c,l), contiguous inner axis of X

// ---------------------------------------------------------------------------
// Stage 1: T1[k][m][q] = sum_n G[k][n][m] * X[b][n][q],  q = c*32 + l
// Plain 64x64-tile fp32 GEMM (A^T * B), all accesses coalesced.
// ---------------------------------------------------------------------------
__global__ __launch_bounds__(256) void k1_stage1(
    const float* __restrict__ X, const float* __restrict__ G,
    float* __restrict__ T1, int b) {
  __shared__ float Gs[16][64];   // Gs[n][m]
  __shared__ float Xs[16][64];   // Xs[n][q]
  const int tid = threadIdx.x;
  const int k  = blockIdx.z;
  const int m0 = blockIdx.y * 64;
  const int q0 = blockIdx.x * 64;
  const int tm = tid >> 4;          // 0..15
  const int tq = tid & 15;          // 0..15
  const int row = tid >> 4;         // staging row (n)
  const int col = (tid & 15) * 4;   // staging col

  const float* Gp = G + (size_t)k * NNODE * NNODE + (size_t)row * NNODE + m0 + col;
  const float* Xp = X + (size_t)b * NNODE * NQ   + (size_t)row * NQ    + q0 + col;

  float acc[4][4] = {};

  for (int n0 = 0; n0 < NNODE; n0 += 16) {
    *(float4*)&Gs[row][col] = *(const float4*)(Gp + (size_t)n0 * NNODE);
    *(float4*)&Xs[row][col] = *(const float4*)(Xp + (size_t)n0 * NQ);
    __syncthreads();
#pragma unroll
    for (int nn = 0; nn < 16; ++nn) {
      const float4 a = *(const float4*)&Gs[nn][tm * 4];
      const float4 x = *(const float4*)&Xs[nn][tq * 4];
      const float av[4] = {a.x, a.y, a.z, a.w};
      const float xv[4] = {x.x, x.y, x.z, x.w};
#pragma unroll
      for (int i = 0; i < 4; ++i)
#pragma unroll
        for (int j = 0; j < 4; ++j) acc[i][j] += av[i] * xv[j];
    }
    __syncthreads();
  }

  float* O = T1 + ((size_t)k * NNODE + m0 + tm * 4) * NQ + q0 + tq * 4;
#pragma unroll
  for (int i = 0; i < 4; ++i) {
    float4 v;
    v.x = acc[i][0]; v.y = acc[i][1]; v.z = acc[i][2]; v.w = acc[i][3];
    *(float4*)(O + (size_t)i * NQ) = v;
  }
}

// ---------------------------------------------------------------------------
// Stage 2+3 fused, per b. Tile: 8 m-rows x 16 d-cols. 256 threads:
//   ch = tid&1 (c-half, later h-half), td = (tid>>1)&15, tm = tid>>5.
// Per l: z[k*3+j] = sum_c T1[k][m][c*32+l] * G[j][c][d]  (c-split + shfl_xor),
// then acc[h] += z[kj] * W[(kj)*32 + l][h] over the thread's 32-h half.
// Epilogue: + bias, ReLU, coalesced store.
// ---------------------------------------------------------------------------
__global__ __launch_bounds__(256, 2) void k2_fused(
    const float* __restrict__ T1, const float* __restrict__ G,
    const float* __restrict__ W, const float* __restrict__ bias,
    float* __restrict__ out, int b) {
  __shared__ float T1s[NK][8][260];    // [k][m-sub][c]   (pad 260: even banks)
  __shared__ float Gsh[NK][16][260];   // [j][d-sub][c]
  __shared__ float Wsh[9][64];         // W rows for current l

  const int tid = threadIdx.x;
  const int d0 = blockIdx.x * 16;
  const int m0 = blockIdx.y * 8;
  const int ch = tid & 1;
  const int td = (tid >> 1) & 15;
  const int tm = tid >> 5;

  // Gsh[j][dd][c] = G[j][c][d0+dd]  (loaded once; l-invariant)
#pragma unroll
  for (int e = 0; e < 48; ++e) {
    int f = e * 256 + tid;
    int dd = f & 15, c = (f >> 4) & 255, j = f >> 12;
    Gsh[j][dd][c] = G[(size_t)(j * NNODE + c) * NNODE + d0 + dd];
  }

  float acc[32] = {};

  for (int l = 0; l < NL; ++l) {
    __syncthreads();  // also covers Gsh on first iteration
    // T1s[k][mm][c] = T1[k][m0+mm][c*32 + l]   (strided gather, L2/L3-served)
#pragma unroll
    for (int e = 0; e < 24; ++e) {
      int f = e * 256 + tid;
      int c = f & 255, mm = (f >> 8) & 7, k = f >> 11;
      T1s[k][mm][c] = T1[(size_t)(k * NNODE + m0 + mm) * NQ + (c << 5) + l];
    }
    // Wsh[kj][h] = W[(kj*32 + l)*64 + h]
    for (int e = tid; e < 9 * NH; e += 256) {
      int kj = e >> 6, h = e & 63;
      Wsh[kj][h] = W[(kj * NL + l) * NH + h];
    }
    __syncthreads();

    float z[9] = {};
    const float* a0 = &T1s[0][tm][ch * 128];
    const float* a1 = &T1s[1][tm][ch * 128];
    const float* a2 = &T1s[2][tm][ch * 128];
    const float* g0 = &Gsh[0][td][ch * 128];
    const float* g1 = &Gsh[1][td][ch * 128];
    const float* g2 = &Gsh[2][td][ch * 128];
#pragma unroll 4
    for (int c = 0; c < 128; c += 4) {
      float4 A[3], Bv[3];
      A[0]  = *(const float4*)(a0 + c);
      A[1]  = *(const float4*)(a1 + c);
      A[2]  = *(const float4*)(a2 + c);
      Bv[0] = *(const float4*)(g0 + c);
      Bv[1] = *(const float4*)(g1 + c);
      Bv[2] = *(const float4*)(g2 + c);
#pragma unroll
      for (int kk = 0; kk < 3; ++kk)
#pragma unroll
        for (int jj = 0; jj < 3; ++jj) {
          z[kk * 3 + jj] += A[kk].x * Bv[jj].x;
          z[kk * 3 + jj] += A[kk].y * Bv[jj].y;
          z[kk * 3 + jj] += A[kk].z * Bv[jj].z;
          z[kk * 3 + jj] += A[kk].w * Bv[jj].w;
        }
    }
    // combine the two c-halves (lanes 2t <-> 2t+1, same wave)
#pragma unroll
    for (int i = 0; i < 9; ++i) z[i] += __shfl_xor(z[i], 1);

    // Stage 3: rank-1 update of this thread's 32-h half
#pragma unroll
    for (int kj = 0; kj < 9; ++kj) {
      const float zz = z[kj];
      const float* wr = &Wsh[kj][ch * 32];
#pragma unroll
      for (int h = 0; h < 32; h += 4) {
        float4 w4 = *(const float4*)(wr + h);
        acc[h + 0] += zz * w4.x;
        acc[h + 1] += zz * w4.y;
        acc[h + 2] += zz * w4.z;
        acc[h + 3] += zz * w4.w;
      }
    }
  }

  const float* bp = bias + ch * 32;
  float* op = out + (((size_t)b * NNODE + m0 + tm) * NNODE + d0 + td) * NH + ch * 32;
#pragma unroll
  for (int h = 0; h < 32; h += 4) {
    float4 v;
    v.x = fmaxf(acc[h + 0] + bp[h + 0], 0.f);
    v.y = fmaxf(acc[h + 1] + bp[h + 1], 0.f);
    v.z = fmaxf(acc[h + 2] + bp[h + 2], 0.f);
    v.w = fmaxf(acc[h + 3] + bp[h + 3], 0.f);
    *(float4*)(op + h) = v;
  }
}

extern "C" void kernel_launch(void* const* d_in, const int* in_sizes, int n_in,
                              void* d_out, int out_size, void* d_ws, size_t ws_size,
                              hipStream_t stream) {
  const float* X    = (const float*)d_in[0];
  const float* G    = (const float*)d_in[1];
  const float* W    = (const float*)d_in[2];
  const float* bias = (const float*)d_in[3];
  float* out = (float*)d_out;
  float* T1  = (float*)d_ws;   // needs NK*NNODE*NQ*4 = 25,165,824 B

  for (int b = 0; b < NBATCH; ++b) {
    k1_stage1<<<dim3(NQ / 64, NNODE / 64, NK), 256, 0, stream>>>(X, G, T1, b);
    k2_fused<<<dim3(NNODE / 16, NNODE / 8), 256, 0, stream>>>(T1, G, W, bias, out, b);
  }
}

// Round 2
// 463.278 us; speedup vs baseline: 16.3905x; 16.3905x over previous
//
#include <hip/hip_runtime.h>
#include <hip/hip_bf16.h>

#define NB 8
#define NN 256
#define NL 32
#define NQ 8192   // = NN*NL
#define NH 64

typedef __attribute__((ext_vector_type(8))) short short8v;
typedef __attribute__((ext_vector_type(4))) float float4v;

static __device__ __forceinline__ ushort f2bf(float f) {
  __hip_bfloat16 h = __float2bfloat16(f);
  return *reinterpret_cast<const ushort*>(&h);
}

// ---------------------------------------------------------------------------
// Gt[k][m][n] = bf16(G[k][n][m])  — serves as stage-1 A and stage-2 B^T.
// ---------------------------------------------------------------------------
__global__ __launch_bounds__(256) void prep_g(const float* __restrict__ G,
                                              ushort* __restrict__ Gt) {
  __shared__ float t[32][33];
  const int k = blockIdx.z, m0 = blockIdx.x * 32, n0 = blockIdx.y * 32;
  const int tid = threadIdx.x;
  const int c = tid & 31, r8 = tid >> 5;
#pragma unroll
  for (int i = 0; i < 4; ++i) {
    int r = r8 + i * 8;
    t[r][c] = G[((size_t)k * NN + n0 + r) * NN + m0 + c];
  }
  __syncthreads();
#pragma unroll
  for (int i = 0; i < 4; ++i) {
    int rm = r8 + i * 8;
    Gt[((size_t)k * NN + m0 + rm) * NN + n0 + c] = f2bf(t[c][rm]);
  }
}

// ---------------------------------------------------------------------------
// Wt[h][kjl] = bf16(W[kjl][h])   (64 x 288)
// ---------------------------------------------------------------------------
__global__ __launch_bounds__(256) void prep_w(const float* __restrict__ W,
                                              ushort* __restrict__ Wt) {
  const int tid = threadIdx.x;
#pragma unroll
  for (int i = 0; i < 18; ++i) {
    int g = i * 256 + tid;            // 4608 float4 groups
    int r = g >> 4;                   // kjl row 0..287
    int h4 = (g & 15) * 4;
    float4 w = *(const float4*)(W + (size_t)r * NH + h4);
    Wt[(size_t)(h4 + 0) * 288 + r] = f2bf(w.x);
    Wt[(size_t)(h4 + 1) * 288 + r] = f2bf(w.y);
    Wt[(size_t)(h4 + 2) * 288 + r] = f2bf(w.z);
    Wt[(size_t)(h4 + 3) * 288 + r] = f2bf(w.w);
  }
}

// ---------------------------------------------------------------------------
// Xt[q'][n] = bf16(X[b][n][q]),  q = c*32+l,  q' = l*256+c   (per b)
// ---------------------------------------------------------------------------
__global__ __launch_bounds__(256) void prep_x(const float* __restrict__ Xb,
                                              ushort* __restrict__ Xt) {
  __shared__ float t[32][33];
  const int qt = blockIdx.x;          // node-c tile index (q0 = qt*32)
  const int n0 = blockIdx.y * 32;
  const int tid = threadIdx.x;
  const int c = tid & 31, r8 = tid >> 5;
  const size_t q0 = (size_t)qt * 32;
#pragma unroll
  for (int i = 0; i < 4; ++i) {
    int r = r8 + i * 8;               // n offset
    t[r][c] = Xb[(size_t)(n0 + r) * NQ + q0 + c];
  }
  __syncthreads();
#pragma unroll
  for (int i = 0; i < 4; ++i) {
    int l = r8 + i * 8;               // within-tile q offset == l
    // q' = l*256 + qt ; column n0 + c
    Xt[((size_t)l * NN + qt) * NN + n0 + c] = f2bf(t[c][l]);
  }
}

// ---------------------------------------------------------------------------
// Generic bf16 MFMA GEMM:  C[M][N] = A[M][K] * Bt[N][K]^T   (all bf16, fp32 acc)
// Block 256 thr = 4 waves (2x2), tile 128x128, wave tile 64x64 = 4x4 frags,
// K-step 32 via mfma_f32_16x16x32_bf16.
// z-offsets: A += (z/3)*aDs + (z%3)*aMs ; Bt += (z/3)*bDs + (z%3)*bMs ; C += z*cs
// ---------------------------------------------------------------------------
__global__ __launch_bounds__(256) void gemm_bt(
    const ushort* __restrict__ A, const ushort* __restrict__ Bt,
    ushort* __restrict__ C, int N, int K,
    size_t aDs, size_t aMs, size_t bDs, size_t bMs, size_t cs) {
  __shared__ short As[128][40];
  __shared__ short Bs[128][40];
  const int z = blockIdx.z;
  const int zd = z / 3, zm = z % 3;
  A  += (size_t)zd * aDs + (size_t)zm * aMs;
  Bt += (size_t)zd * bDs + (size_t)zm * bMs;
  C  += (size_t)z * cs;
  const int n0 = blockIdx.x * 128;
  const int m0 = blockIdx.y * 128;
  const int tid = threadIdx.x;
  const int lane = tid & 63;
  const int w = tid >> 6;
  const int wr = (w >> 1) * 64, wc = (w & 1) * 64;
  const int sr = tid >> 1, sc = (tid & 1) * 16;
  const int fr = lane & 15, fg = (lane >> 4) * 8;

  float4v acc[4][4] = {};

  const ushort* ap = A + (size_t)(m0 + sr) * K + sc;
  const ushort* bp = Bt + (size_t)(n0 + sr) * K + sc;

  for (int kk = 0; kk < K; kk += 32) {
    *(float4*)&As[sr][sc]     = *(const float4*)(ap + kk);
    *(float4*)&As[sr][sc + 8] = *(const float4*)(ap + kk + 8);
    *(float4*)&Bs[sr][sc]     = *(const float4*)(bp + kk);
    *(float4*)&Bs[sr][sc + 8] = *(const float4*)(bp + kk + 8);
    __syncthreads();
    short8v af[4], bf[4];
#pragma unroll
    for (int i = 0; i < 4; ++i)
      af[i] = *(const short8v*)&As[wr + i * 16 + fr][fg];
#pragma unroll
    for (int j = 0; j < 4; ++j)
      bf[j] = *(const short8v*)&Bs[wc + j * 16 + fr][fg];
#pragma unroll
    for (int i = 0; i < 4; ++i)
#pragma unroll
      for (int j = 0; j < 4; ++j)
        acc[i][j] = __builtin_amdgcn_mfma_f32_16x16x32_bf16(af[i], bf[j],
                                                            acc[i][j], 0, 0, 0);
    __syncthreads();
  }

  const int rbase = (lane >> 4) * 4;
#pragma unroll
  for (int i = 0; i < 4; ++i) {
    const int row = m0 + wr + i * 16 + rbase;
#pragma unroll
    for (int j = 0; j < 4; ++j) {
      const int col = n0 + wc + j * 16 + fr;
      ushort* cp = C + (size_t)row * N + col;
#pragma unroll
      for (int r = 0; r < 4; ++r)
        cp[(size_t)r * N] = f2bf(acc[i][j][r]);
    }
  }
}

// ---------------------------------------------------------------------------
// Stage 3: out[b][m][d][h] = relu( sum_{kj,l} T2[kj][(m,l)][d] * Wt[h][kj*32+l] + bias[h] )
// Block: (d-tile 64) x (m). K-step = one (k,j) pair (K=32). Wt resident in LDS.
// ---------------------------------------------------------------------------
__global__ __launch_bounds__(256) void s3_fused(
    const ushort* __restrict__ T2, const ushort* __restrict__ Wt,
    const float* __restrict__ bias, float* __restrict__ out, int b) {
  __shared__ short Ws[64][296];
  __shared__ short As[64][40];
  const int tid = threadIdx.x;
  const int d0 = blockIdx.x * 64;
  const int m = blockIdx.y;

  // load Wt[64][288] into padded LDS
#pragma unroll
  for (int i = 0; i < 9; ++i) {
    int g = i * 256 + tid;            // 2304 groups of 8
    int row = g / 36;
    int c8 = (g % 36) * 8;
    *(float4*)&Ws[row][c8] = *(const float4*)(Wt + (size_t)row * 288 + c8);
  }

  const int lane = tid & 63;
  const int w = tid >> 6;
  const int wr = (w >> 1) * 32, wc = (w & 1) * 32;
  const int fr = lane & 15, fg = (lane >> 4) * 8;
  const int sl = tid >> 3, se = (tid & 7) * 8;

  float4v acc[2][2] = {};

  for (int kj = 0; kj < 9; ++kj) {
    __syncthreads();                  // As reuse guard (+ first-iter Ws)
    short8v v = *(const short8v*)(T2 + ((size_t)kj * NQ + (size_t)m * NL + sl) * NN + d0 + se);
#pragma unroll
    for (int e = 0; e < 8; ++e) As[se + e][sl] = v[e];
    __syncthreads();
    short8v af[2], bf[2];
#pragma unroll
    for (int i = 0; i < 2; ++i)
      af[i] = *(const short8v*)&As[wr + i * 16 + fr][fg];
#pragma unroll
    for (int j = 0; j < 2; ++j)
      bf[j] = *(const short8v*)&Ws[wc + j * 16 + fr][kj * 32 + fg];
#pragma unroll
    for (int i = 0; i < 2; ++i)
#pragma unroll
      for (int j = 0; j < 2; ++j)
        acc[i][j] = __builtin_amdgcn_mfma_f32_16x16x32_bf16(af[i], bf[j],
                                                            acc[i][j], 0, 0, 0);
  }

  const int rbase = (lane >> 4) * 4;
#pragma unroll
  for (int i = 0; i < 2; ++i) {
#pragma unroll
    for (int j = 0; j < 2; ++j) {
      const int h = wc + j * 16 + fr;
      const float bh = bias[h];
#pragma unroll
      for (int r = 0; r < 4; ++r) {
        const int d = d0 + wr + i * 16 + rbase + r;
        out[(((size_t)b * NN + m) * NN + d) * NH + h] = fmaxf(acc[i][j][r] + bh, 0.f);
      }
    }
  }
}

extern "C" void kernel_launch(void* const* d_in, const int* in_sizes, int n_in,
                              void* d_out, int out_size, void* d_ws, size_t ws_size,
                              hipStream_t stream) {
  (void)in_sizes; (void)n_in; (void)out_size; (void)ws_size;
  const float* X    = (const float*)d_in[0];
  const float* G    = (const float*)d_in[1];
  const float* W    = (const float*)d_in[2];
  const float* bias = (const float*)d_in[3];
  float* out = (float*)d_out;

  char* p = (char*)d_ws;
  ushort* Gt = (ushort*)p;  p += (size_t)3 * NN * NN * 2;        // 393 KB
  ushort* Wt = (ushort*)p;  p += (size_t)NH * 288 * 2;           // 37 KB
  ushort* Xt = (ushort*)p;  p += (size_t)NQ * NN * 2;            // 4 MB
  ushort* T1 = (ushort*)p;  p += (size_t)3 * NQ * NN * 2;        // 12.6 MB
  ushort* T2 = (ushort*)p;                                       // 37.7 MB
  const size_t SL = (size_t)NN * NQ;                             // 2097152

  prep_g<<<dim3(8, 8, 3), 256, 0, stream>>>(G, Gt);
  prep_w<<<dim3(1), 256, 0, stream>>>(W, Wt);

  for (int b = 0; b < NB; ++b) {
    prep_x<<<dim3(256, 8), 256, 0, stream>>>(X + (size_t)b * NN * NQ, Xt);
    // Stage 1: z=k : A = Gt[k] (256x256), Bt = Xt (8192x256), C = T1[k] (256x8192)
    gemm_bt<<<dim3(64, 2, 3), 256, 0, stream>>>(Gt, Xt, T1, NQ, NN,
        0, (size_t)NN * NN, 0, 0, SL);
    // Stage 2: z=kj : A = T1[k] (8192x256), Bt = Gt[j] (256x256), C = T2[kj] (8192x256)
    gemm_bt<<<dim3(2, 64, 9), 256, 0, stream>>>(T1, Gt, T2, NN, NN,
        SL, 0, 0, (size_t)NN * NN, SL);
    // Stage 3
    s3_fused<<<dim3(4, 256), 256, 0, stream>>>(T2, Wt, bias, out, b);
  }
}